// Round 1
// 1291.460 us; speedup vs baseline: 1.9579x; 1.9579x over previous
//
#include <hip/hip_runtime.h>
#include <cstdint>

// Problem dims (fixed by reference)
#define B_   128
#define T_   32
#define IN_  2048
#define H_   2048
#define OUT_ 512

// address-space helper types for global_load_lds
typedef __attribute__((address_space(1))) const void* gas_cp;
typedef __attribute__((address_space(3))) void* las_p;

// ---------- kernel 1: transpose spikes ----------
// in:  spike_data [B][IN][T] f32 (values exactly 0.0/1.0)
// out: Xt [T*B][IN] f32 (same bit values, relocated)
__global__ __launch_bounds__(256) void k_transpose(const float* __restrict__ in,
                                                   float* __restrict__ Xt) {
    int idx = blockIdx.x * 256 + threadIdx.x;   // b*IN + i
    int b = idx >> 11;
    int i = idx & (IN_ - 1);
    const float4* p = (const float4*)(in + (size_t)idx * T_);
#pragma unroll
    for (int q = 0; q < 8; ++q) {
        float4 v = p[q];
        int t = q * 4;
        Xt[((size_t)((t + 0) * B_ + b) << 11) + i] = v.x;
        Xt[((size_t)((t + 1) * B_ + b) << 11) + i] = v.y;
        Xt[((size_t)((t + 2) * B_ + b) << 11) + i] = v.z;
        Xt[((size_t)((t + 3) * B_ + b) << 11) + i] = v.w;
    }
}

// ---------- kernel 2: fp32 GEMM, KC=512 block chain (AOCL-BLIS schedule) -----
// Exact-chain semantics preserved verbatim from the verified kernel:
//   C = ((chain(0..511) + chain(512..1023)) + chain(1024..1535)) + chain(1536..2047)
// ascending-k FMA chain per output inside each 512-block, plain adds joining.
// NEW this round: async double-buffered staging via global_load_lds (width 16).
//  - LDS dest is linear (wave-uniform base + lane*16); the granule rotation is
//    applied by PRE-SWIZZLING the per-lane global source address (rule #21):
//    LDS granule L holds source granule s = ((L&7) - rot(L>>3)) & 7 of row L>>3,
//    producing the identical LDS image the old ds_write staging produced.
//  - Prefetch of tile t+1 issued right after the top-of-iter barrier; consumed
//    next iteration (T3 minimum 2-phase). The barrier's vmcnt(0) drain lands
//    after ~2000 FMA issue-cycles -> staging latency fully hidden.
// Tiles: BM=64 x BN=128 x BK=32, 256 threads, per-thread 4m x 8n. LDS 48 KB.
__global__ __launch_bounds__(256)
void k_gemm_seq(const float* __restrict__ A, const float* __restrict__ W,
                float* __restrict__ C, int M, int N, int K) {
    constexpr int BM = 64, BN = 128, BK = 32;
    constexpr int NT = 8;                       // n per thread (BN/16)
    constexpr int BUFF = (BM + BN) * BK;        // 6144 floats = 24 KB
    __shared__ alignas(16) float lds[2][BUFF];  // 48 KB double-buffered

    const int tid = threadIdx.x;
    const int tx  = tid & 15;        // n direction
    const int ty  = tid >> 4;        // m direction
    const int m0  = blockIdx.y * BM;
    const int n0  = blockIdx.x * BN;
    const int w   = tid >> 6;        // wave id 0..3

    // Pre-swizzled per-lane global sources + per-wave LDS dest offsets.
    // A tile: 64 rows x 8 granules = 512 granules -> 2 glds per thread.
    const float* srcA[2];
    int dstA[2];
#pragma unroll
    for (int q = 0; q < 2; ++q) {
        int L = q * 256 + tid;                       // linear granule index
        int r = L >> 3;                              // row
        int s = ((L & 7) - ((r + (r >> 4)) & 7)) & 7;// source granule (inv rot)
        srcA[q] = A + (size_t)(m0 + r) * K + s * 4;
        dstA[q] = q * 1024 + w * 256;                // float offset (wave-uniform)
    }
    // W tile: 128 rows x 8 granules = 1024 granules -> 4 glds per thread.
    const float* srcW[4];
    int dstW[4];
#pragma unroll
    for (int q = 0; q < 4; ++q) {
        int L = q * 256 + tid;
        int r = L >> 3;
        int s = ((L & 7) - ((r + (r >> 4)) & 7)) & 7;
        srcW[q] = W + (size_t)(n0 + r) * K + s * 4;
        dstW[q] = BM * BK + q * 1024 + w * 256;
    }

    float acc[4][NT];                // in-block FMA chain
    float tot[4][NT];                // cross-block joins (plain adds)
#pragma unroll
    for (int i = 0; i < 4; ++i)
#pragma unroll
        for (int j = 0; j < NT; ++j) { acc[i][j] = 0.0f; tot[i][j] = 0.0f; }

    const int nkt = K / BK;

    // prologue: stage tile 0 into buffer 0
#pragma unroll
    for (int q = 0; q < 2; ++q) {
        __builtin_amdgcn_global_load_lds((gas_cp)srcA[q], (las_p)&lds[0][dstA[q]], 16, 0, 0);
        srcA[q] += BK;
    }
#pragma unroll
    for (int q = 0; q < 4; ++q) {
        __builtin_amdgcn_global_load_lds((gas_cp)srcW[q], (las_p)&lds[0][dstW[q]], 16, 0, 0);
        srcW[q] += BK;
    }

    int cur = 0;
    for (int kt = 0; kt < nkt; ++kt) {
        __syncthreads();             // drains vmcnt: buf[cur] staged & visible

        if (kt + 1 < nkt) {          // async prefetch of next tile into buf^1
            int nb = cur ^ 1;
#pragma unroll
            for (int q = 0; q < 2; ++q) {
                __builtin_amdgcn_global_load_lds((gas_cp)srcA[q], (las_p)&lds[nb][dstA[q]], 16, 0, 0);
                srcA[q] += BK;
            }
#pragma unroll
            for (int q = 0; q < 4; ++q) {
                __builtin_amdgcn_global_load_lds((gas_cp)srcW[q], (las_p)&lds[nb][dstW[q]], 16, 0, 0);
                srcW[q] += BK;
            }
        }

        const float* At = &lds[cur][0];
        const float* Wt = &lds[cur][BM * BK];

#pragma unroll
        for (int gk = 0; gk < 8; ++gk) {        // granule = 4 consecutive k
            float4 av[4], wv[NT];
#pragma unroll
            for (int i = 0; i < 4; ++i) {
                int r = ty + 16 * i;
                int rot = (r + (r >> 4)) & 7;
                av[i] = *(const float4*)&At[r * BK + (((gk + rot) & 7) << 2)];
            }
#pragma unroll
            for (int j = 0; j < NT; ++j) {
                int r = tx + 16 * j;
                int rot = (r + (r >> 4)) & 7;
                wv[j] = *(const float4*)&Wt[r * BK + (((gk + rot) & 7) << 2)];
            }
            // strictly ascending k within the granule; 32 independent chains
#pragma unroll
            for (int q = 0; q < 4; ++q)
#pragma unroll
                for (int i = 0; i < 4; ++i)
#pragma unroll
                    for (int j = 0; j < NT; ++j)
                        acc[i][j] = __builtin_fmaf(((const float*)&av[i])[q],
                                                   ((const float*)&wv[j])[q],
                                                   acc[i][j]);
        }

        // KC=512 block boundary: fold in-block chain into the C-join
        // accumulator with a plain fp32 add (BLIS C += A_blk*B_blk).
        if (((kt + 1) & 15) == 0) {
#pragma unroll
            for (int i = 0; i < 4; ++i)
#pragma unroll
                for (int j = 0; j < NT; ++j) {
                    tot[i][j] = tot[i][j] + acc[i][j];
                    acc[i][j] = 0.0f;
                }
        }
        cur ^= 1;
    }

#pragma unroll
    for (int i = 0; i < 4; ++i)
#pragma unroll
        for (int j = 0; j < NT; ++j)
            C[(size_t)(m0 + ty + 16 * i) * N + (n0 + tx + 16 * j)] = tot[i][j];
}

// ---------- kernel 3: LIF scan over t for hidden layers (fp32, numpy order) --
// volt = (0.5f*v)*(1-s) + x + b ; spike = volt > 0.5f     (biases are zero)
__global__ __launch_bounds__(256) void k_scan_h(const float* __restrict__ Acc,
                                                const float* __restrict__ v_init,
                                                const float* __restrict__ s_init,
                                                const float* __restrict__ bias,
                                                float* __restrict__ Sout) {
    int idx = blockIdx.x * 256 + threadIdx.x;  // b*H + h
    int h = idx & (H_ - 1);
    float v = v_init[idx];
    float s = s_init[idx];
    float bb = bias[h];
#pragma unroll
    for (int t = 0; t < T_; ++t) {
        float x = Acc[(size_t)t * (B_ * H_) + idx];
        float d = 0.5f * v;          // exact (power of two)
        d = d * (1.0f - s);          // exact (x{0,1})
        v = d + x;
        v = v + bb;
        s = (v > 0.5f) ? 1.0f : 0.0f;
        Sout[(size_t)t * (B_ * H_) + idx] = s;
    }
}

// ---------- kernel 4: LIF scan + spike count for output layer ----------
__global__ __launch_bounds__(256) void k_scan_o(const float* __restrict__ Acc,
                                                const float* __restrict__ v_init,
                                                const float* __restrict__ s_init,
                                                const float* __restrict__ bias,
                                                float* __restrict__ out) {
    int idx = blockIdx.x * 256 + threadIdx.x;  // b*OUT + o
    int o = idx & (OUT_ - 1);
    float v = v_init[idx];
    float s = s_init[idx];
    float bb = bias[o];
    float acc = 0.0f;
#pragma unroll
    for (int t = 0; t < T_; ++t) {
        float x = Acc[(size_t)t * (B_ * OUT_) + idx];
        float d = 0.5f * v;
        d = d * (1.0f - s);
        v = d + x;
        v = v + bb;
        s = (v > 0.5f) ? 1.0f : 0.0f;
        acc += s;                    // integer-valued, exact in fp32
    }
    out[idx] = acc;
}

// ---------- launch ----------

extern "C" void kernel_launch(void* const* d_in, const int* in_sizes, int n_in,
                              void* d_out, int out_size, void* d_ws, size_t ws_size,
                              hipStream_t stream) {
    const float* spike_data = (const float*)d_in[0];
    const float* h0_volt  = (const float*)d_in[1];
    const float* h0_spike = (const float*)d_in[2];
    const float* h1_volt  = (const float*)d_in[3];
    const float* h1_spike = (const float*)d_in[4];
    const float* o_volt   = (const float*)d_in[5];
    const float* o_spike  = (const float*)d_in[6];
    const float* W0 = (const float*)d_in[7];
    const float* b0 = (const float*)d_in[8];
    const float* W1 = (const float*)d_in[9];
    const float* b1 = (const float*)d_in[10];
    const float* Wo = (const float*)d_in[11];
    const float* bo = (const float*)d_in[12];
    float* out = (float*)d_out;

    // workspace layout (96 MB)
    char* ws = (char*)d_ws;
    const size_t MB = (size_t)1 << 20;
    float* Xt = (float*)(ws);             // 32 MB [T*B][IN]; reused as S1
    float* S0 = (float*)(ws + 32 * MB);   // 32 MB [T*B][H]
    float* Ab = (float*)(ws + 64 * MB);   // 32 MB [T*B][H] (or [T*B][OUT])
    float* S1 = Xt;                       // Xt dead after GEMM0

    const int M = T_ * B_;   // 4096

    k_transpose<<<(B_ * IN_) / 256, 256, 0, stream>>>(spike_data, Xt);

    // layer 0: A0 = Xt @ W0^T   [4096,2048] x [2048,2048]
    k_gemm_seq<<<dim3(H_ / 128, M / 64), 256, 0, stream>>>(Xt, W0, Ab, M, H_, IN_);
    k_scan_h<<<(B_ * H_) / 256, 256, 0, stream>>>(Ab, h0_volt, h0_spike, b0, S0);

    // layer 1: A1 = S0 @ W1^T
    k_gemm_seq<<<dim3(H_ / 128, M / 64), 256, 0, stream>>>(S0, W1, Ab, M, H_, H_);
    k_scan_h<<<(B_ * H_) / 256, 256, 0, stream>>>(Ab, h1_volt, h1_spike, b1, S1);

    // output: Ao = S1 @ Wo^T   [4096,2048] x [2048,512]
    k_gemm_seq<<<dim3(OUT_ / 128, M / 64), 256, 0, stream>>>(S1, Wo, Ab, M, OUT_, H_);
    k_scan_o<<<(B_ * OUT_) / 256, 256, 0, stream>>>(Ab, o_volt, o_spike, bo, out);

    (void)in_sizes; (void)n_in; (void)out_size; (void)ws_size;
}